// Round 1
// baseline (64941.589 us; speedup 1.0000x reference)
//
#include <hip/hip_runtime.h>

#define H    50
#define T    65536
#define NTHREADS 512

// ws layout (floats) — unchanged from previous (verified) version.
#define WC1_OFF 0        // 200*64
#define WC2_OFF 12800    // 200*128
#define BC1_OFF 38400    // 200
#define BC2_OFF 38600    // 200

// Prep: permute rows (orig r = gate*50+j  ->  new r' = j*4+gate) and pad cols.
// Wc1: 200 x 64  : cols 0..6 = W_ih1[:,0:7], col 7 = W_ih1[:,7] (err), 8..57 = W_hh1, 58..63 = 0
// Wc2: 200 x 128 : cols 0..49 = W_ih2, 50..99 = W_hh2, 100..127 = 0
__global__ void prep_kernel(const float* __restrict__ Wih1, const float* __restrict__ Whh1,
                            const float* __restrict__ bih1, const float* __restrict__ bhh1,
                            const float* __restrict__ Wih2, const float* __restrict__ Whh2,
                            const float* __restrict__ bih2, const float* __restrict__ bhh2,
                            float* __restrict__ ws) {
  int idx = blockIdx.x * blockDim.x + threadIdx.x;
  if (idx < 200 * 64) {
    int nr = idx >> 6, c = idx & 63;
    int j = nr >> 2, gate = nr & 3, r = gate * 50 + j;
    float v = 0.f;
    if (c < 8) v = Wih1[r * 8 + c];
    else if (c < 58) v = Whh1[r * 50 + (c - 8)];
    ws[WC1_OFF + idx] = v;
  }
  if (idx < 200 * 128) {
    int nr = idx >> 7, c = idx & 127;
    int j = nr >> 2, gate = nr & 3, r = gate * 50 + j;
    float v = 0.f;
    if (c < 50) v = Wih2[r * 50 + c];
    else if (c < 100) v = Whh2[r * 50 + (c - 50)];
    ws[WC2_OFF + idx] = v;
  }
  if (idx < 200) {
    int j = idx >> 2, gate = idx & 3, r = gate * 50 + j;
    ws[BC1_OFF + idx] = bih1[r] + bhh1[r];
    ws[BC2_OFF + idx] = bih2[r] + bhh2[r];
  }
}

__device__ __forceinline__ float sigm(float x) {
  return __builtin_amdgcn_rcpf(1.f + __expf(-x));
}
__device__ __forceinline__ float tanh_(float x) {
  return 1.f - 2.f * __builtin_amdgcn_rcpf(1.f + __expf(2.f * x));
}
// LDS-only barrier: no vmcnt drain, so global prefetch loads and y-stores
// pipeline across steps.
__device__ __forceinline__ void bar() {
  asm volatile("s_waitcnt lgkmcnt(0)\n\ts_barrier" ::: "memory");
}
// 0xB1 = quad_perm(1,0,3,2) = xor1 ; 0x4E = quad_perm(2,3,0,1) = xor2
// 0x141 = row_half_mirror (completes 8-lane reduce after xor1+xor2)
// 0x140 = row_mirror (completes 16-lane reduce)
template<int CTRL>
__device__ __forceinline__ float dpp_add(float x) {
  int y = __builtin_amdgcn_mov_dpp(__float_as_int(x), CTRL, 0xF, 0xF, true);
  return x + __int_as_float(y);
}
template<int CTRL>
__device__ __forceinline__ float dpp_mov(float x) {
  return __int_as_float(__builtin_amdgcn_mov_dpp(__float_as_int(x), CTRL, 0xF, 0xF, true));
}

// ============================================================================
// 2-phase schedule (was 3). err enters cell-1 gates LINEARLY (col 7), so the
// full cell-1 matvec for step t+1 is computed one phase early by waves 4-7
// ("helpers") while waves 0-3 do cell-2 for step t. Only a 4-FMA correction
// (+ werr*err) remains on the serial path, executed by wave 0 right after the
// y-reduce — err itself never round-trips through LDS (replicated in wave-0
// registers).
//
// Per step t (par = t&1):
//  Phase1: waves 0-3 : cell-2 row-per-lane (row = tid, gate = tid&3):
//            read CIN[par] (=[h1(t) 0..49 | h2(t-1) 50..99]) via broadcast
//            b128, 100 FMA, quad DPP gather -> owner lane (tid&3==0) updates
//            c2, writes h2(t) -> CIN[par^1][50+u], wy -> WY[u].
//          waves 4-7 : cell-1 partial for t+1 (row = tid-256): read
//            AIN[par^1] (=[x(t+1) 0..6 | 0 | h1(t) 8..57]), 64 FMA,
//            PART[row] = dot + bias.
//  bar()
//  Phase2: wave 0    : y(t) = butterfly(WY)+bo; out[t]; err update (uniform
//            in regs); gates(t+1) = PART[4l..]+werr*err; c1, h1(t+1) ->
//            CIN[par^1][l] and AIN[par][8+l].
//          lanes 504-511: publish x(t+2) -> AIN[par][0..6], ACT4[(t+2)&3];
//            prefetch x(t+3) (depth-2, latency hidden across 2 phases).
//  bar()
// ============================================================================
__launch_bounds__(NTHREADS, 2)
__global__ void lstm_kernel(const float* __restrict__ xseq,
                            const float* __restrict__ ws,
                            const float* __restrict__ Wout,
                            const float* __restrict__ bout,
                            float* __restrict__ out) {
  // Dense layouts (reads are wave-broadcast -> no bank conflicts; old phys()
  // chunk padding dropped). Pads must stay exactly 0 forever.
  __shared__ __align__(16) float AIN[2][64];    // [x(7) | 0@7 | h1(50) | 0(6)]
  __shared__ __align__(16) float CIN[2][128];   // [h1(50) | h2(50) | pad]
  __shared__ __align__(16) float PART[256];     // cell-1 partial gates (rows)
  __shared__ __align__(16) float WY[64];        // wo[u]*h2[u], 50..63 = 0
  __shared__ float ACT4[4];                     // act_dist ring, depth 4

  const int tid = threadIdx.x;
  const float* Wc1 = ws + WC1_OFF;
  const float* Wc2 = ws + WC2_OFF;
  const float* bc1 = ws + BC1_OFF;
  const float* bc2 = ws + BC2_OFF;

  for (int i = tid; i < 2 * 64;  i += NTHREADS) ((float*)AIN)[i] = 0.f;
  for (int i = tid; i < 2 * 128; i += NTHREADS) ((float*)CIN)[i] = 0.f;
  for (int i = tid; i < 256;     i += NTHREADS) PART[i] = 0.f;
  if (tid < 64) WY[tid] = 0.f;
  if (tid < 4)  ACT4[tid] = 0.f;

  // Union weight register block: cell-2 lanes use [0..99], helpers [0..63].
  float wreg[100];
  float c1 = 0.f, c2 = 0.f, err = 0.f, xr = 0.f;
  float b2h = 0.f, b1h = 0.f, wo = 0.f, bo = 0.f;
  float werr0 = 0.f, werr1 = 0.f, werr2 = 0.f, werr3 = 0.f;
  // unified activation: act = aA + bA * rcp(1 + exp(sA*x))
  // gate p==2 (g): tanh -> sA=2, aA=1, bA=-2 ; else sigmoid -> sA=-1,aA=0,bA=1
  float sA = -1.f, aA = 0.f, bA = 1.f;

  if (tid < 256) {                       // cell-2 lanes, row = tid
    int row = tid;
    if ((tid & 3) == 2) { sA = 2.f; aA = 1.f; bA = -2.f; }
    if (row < 200) {
      #pragma unroll
      for (int q = 0; q < 25; q++) {
        float4 v = *(const float4*)&Wc2[row * 128 + 4 * q];
        wreg[4*q+0] = v.x; wreg[4*q+1] = v.y; wreg[4*q+2] = v.z; wreg[4*q+3] = v.w;
      }
      b2h = bc2[row];
    } else {                             // dead pad rows -> exact zeros
      #pragma unroll
      for (int q = 0; q < 100; q++) wreg[q] = 0.f;
    }
    if ((tid & 3) == 0) {
      int u = tid >> 2;
      wo = (u < 50) ? Wout[u] : 0.f;
    }
    if (tid < 64) {                      // wave 0: phase-2 worker extras
      bo = bout[0];
      if (tid < 50) {
        werr0 = Wc1[(4 * tid + 0) * 64 + 7];
        werr1 = Wc1[(4 * tid + 1) * 64 + 7];
        werr2 = Wc1[(4 * tid + 2) * 64 + 7];
        werr3 = Wc1[(4 * tid + 3) * 64 + 7];
      }
    }
  } else {                               // helper lanes, row = tid-256
    int row = tid - 256;
    if (row < 200) {
      #pragma unroll
      for (int q = 0; q < 16; q++) {
        float4 v = *(const float4*)&Wc1[row * 64 + 4 * q];
        wreg[4*q+0] = v.x; wreg[4*q+1] = v.y; wreg[4*q+2] = v.z; wreg[4*q+3] = v.w;
      }
      b1h = bc1[row];
    } else {
      #pragma unroll
      for (int q = 0; q < 64; q++) wreg[q] = 0.f;
    }
  }
  __syncthreads();
  // preload x(0) AFTER zeroing (avoid zero-vs-preload race), stage x(1) in xr
  if (tid >= 504) {
    int c = tid - 504;
    float v0 = xseq[c];
    if (c < 7) AIN[0][c] = v0; else ACT4[0] = v0;
    xr = xseq[8 + c];
  }
  __syncthreads();

  auto cell2_phase = [&](int par) {      // tid < 256
    const float* U = CIN[par];
    float a0 = 0.f, a1 = 0.f, a2 = 0.f, a3 = 0.f;
    #pragma unroll
    for (int q = 0; q < 25; q++) {
      float4 u4 = *(const float4*)&U[4 * q];   // wave-broadcast read
      a0 += wreg[4*q+0] * u4.x;
      a1 += wreg[4*q+1] * u4.y;
      a2 += wreg[4*q+2] * u4.z;
      a3 += wreg[4*q+3] * u4.w;
    }
    float a = ((a0 + a1) + (a2 + a3)) + b2h;
    float act = aA + bA * __builtin_amdgcn_rcpf(1.f + __expf(sA * a));
    // quad gather: lane0 of each quad ends with (act=i, x1=f, x2=g, x3=o)
    float x1 = dpp_mov<0xB1>(act);
    float x2 = dpp_mov<0x4E>(act);
    float x3 = dpp_mov<0x4E>(x1);
    if ((tid & 3) == 0) {
      c2 = x1 * c2 + act * x2;           // f*c2 + i*g
      float h2 = x3 * tanh_(c2);         // o*tanh(c2); dead units: exactly 0
      int u = tid >> 2;
      CIN[par ^ 1][50 + u] = h2;
      WY[u] = wo * h2;
    }
  };

  auto helper_phase = [&](int par) {     // tid >= 256, computes PART(t+1)
    const float* Uh = AIN[par ^ 1];
    float a0 = 0.f, a1 = 0.f, a2 = 0.f, a3 = 0.f;
    #pragma unroll
    for (int q = 0; q < 16; q++) {
      float4 u4 = *(const float4*)&Uh[4 * q];  // wave-broadcast read
      a0 += wreg[4*q+0] * u4.x;
      a1 += wreg[4*q+1] * u4.y;
      a2 += wreg[4*q+2] * u4.z;
      a3 += wreg[4*q+3] * u4.w;
    }
    PART[tid - 256] = ((a0 + a1) + (a2 + a3)) + b1h;
  };

  auto phase2 = [&](int t, int par, bool doY) {
    if (tid < 64) {
      int l = tid;
      float4 pq = *(const float4*)&PART[4 * l];   // gates i,f,g,o (partial+b)
      if (doY) {
        float v = WY[l];
        float act = ACT4[t & 3];
        v = dpp_add<0xB1>(v); v = dpp_add<0x4E>(v);
        v = dpp_add<0x141>(v); v = dpp_add<0x140>(v);
        v = v + __int_as_float(__builtin_amdgcn_ds_swizzle(__float_as_int(v), 0x401F));
        float vlo = __int_as_float(__builtin_amdgcn_readlane(__float_as_int(v), 0));
        float vhi = __int_as_float(__builtin_amdgcn_readlane(__float_as_int(v), 32));
        float y = vlo + vhi + bo;
        if (l == 0) out[t] = y;          // fire-and-forget (bar has no vmcnt)
        err = 0.9f * err + 0.1f * (act - y);   // uniform across wave 0
      }
      float gi = sigm (pq.x + werr0 * err);
      float gf = sigm (pq.y + werr1 * err);
      float gg = tanh_(pq.z + werr2 * err);
      float go = sigm (pq.w + werr3 * err);
      c1 = gf * c1 + gi * gg;
      float h1 = go * tanh_(c1);
      if (l < 50) {
        CIN[par ^ 1][l]   = h1;          // for cell-2, phase1(t+1)
        AIN[par][8 + l]   = h1;          // for helpers, phase1(t+1)
      }
    } else if (tid >= 504) {             // loader lanes (wave 7, off-path)
      int c = tid - 504;
      if (c < 7) AIN[par][c] = xr; else ACT4[(t + 2) & 3] = xr;
      int nt = (t + 3 < T) ? t + 3 : T - 1;
      xr = xseq[nt * 8 + c];
    }
  };

  // ---- prologue: pseudo-iteration t = -1 (par = 1), no y/err yet ----
  if (tid >= 256) helper_phase(1);       // PART(0) from AIN[0] = [x(0); h1=0]
  bar();
  phase2(-1, 1, false);                  // h1(0)->CIN[0],AIN[1]; x(1)->AIN[1]
  bar();

  #pragma unroll 1
  for (int t = 0; t < T; t += 2) {
    if (tid < 256) cell2_phase(0); else helper_phase(0);
    bar();
    phase2(t, 0, true);
    bar();
    if (tid < 256) cell2_phase(1); else helper_phase(1);
    bar();
    phase2(t + 1, 1, true);
    bar();
  }
}

extern "C" void kernel_launch(void* const* d_in, const int* in_sizes, int n_in,
                              void* d_out, int out_size, void* d_ws, size_t ws_size,
                              hipStream_t stream) {
  const float* xseq = (const float*)d_in[0];
  const float* Wih1 = (const float*)d_in[1];
  const float* Whh1 = (const float*)d_in[2];
  const float* bih1 = (const float*)d_in[3];
  const float* bhh1 = (const float*)d_in[4];
  const float* Wih2 = (const float*)d_in[5];
  const float* Whh2 = (const float*)d_in[6];
  const float* bih2 = (const float*)d_in[7];
  const float* bhh2 = (const float*)d_in[8];
  const float* Wout = (const float*)d_in[9];
  const float* bout = (const float*)d_in[10];
  float* ws = (float*)d_ws;

  prep_kernel<<<100, 256, 0, stream>>>(Wih1, Whh1, bih1, bhh1,
                                       Wih2, Whh2, bih2, bhh2, ws);
  lstm_kernel<<<1, NTHREADS, 0, stream>>>(xseq, ws, Wout, bout, (float*)d_out);
}